// Round 1
// baseline (1280.888 us; speedup 1.0000x reference)
//
#include <hip/hip_runtime.h>

#define N_TOK 4096
#define C_DIM 256
#define HEADS 8
#define HDIM  32
#define KSPLIT 4
#define QSCALE 0.17677669529663687f

// ---------------------------------------------------------------------------
// Kernel 1: fused QKV projection.  QKV[768][4096] = [wq;wk;wv] @ x
// Q rows (0..255) pre-scaled by 1/sqrt(32).
// 64x64 tile per block, 4x4 per thread, K-chunks of 16.
// ---------------------------------------------------------------------------
__global__ __launch_bounds__(256) void qkv_kernel(
    const float* __restrict__ x,
    const float* __restrict__ wq,
    const float* __restrict__ wk,
    const float* __restrict__ wv,
    float* __restrict__ QKV)
{
  const int bn = blockIdx.x * 64;
  const int by = blockIdx.y;                       // 0..11 (q:0-3, k:4-7, v:8-11)
  const float* W = (by < 4) ? wq : (by < 8) ? wk : wv;
  const int wrow0 = (by & 3) * 64;
  const float scl = (by < 4) ? QSCALE : 1.0f;

  __shared__ float As[16][68];   // [k][m], padded row=272B (16B aligned)
  __shared__ float Bs[16][64];   // [k][n]

  const int t  = threadIdx.x;
  const int tm = (t & 15) * 4;
  const int tn = (t >> 4) * 4;

  float acc[4][4] = {};

  for (int k0 = 0; k0 < C_DIM; k0 += 16) {
    // stage W tile (64 rows x 16 k), transposed into As[k][m]
    {
      const int r  = t >> 2;
      const int kk = (t & 3) * 4;
      const float4 w4 = *reinterpret_cast<const float4*>(&W[(wrow0 + r) * C_DIM + k0 + kk]);
      As[kk + 0][r] = w4.x; As[kk + 1][r] = w4.y;
      As[kk + 2][r] = w4.z; As[kk + 3][r] = w4.w;
    }
    // stage x tile (16 k x 64 n), coalesced
    {
      const int kb = t >> 6;     // 0..3
      const int nn = t & 63;
      #pragma unroll
      for (int c2 = 0; c2 < 4; c2++)
        Bs[kb + c2 * 4][nn] = x[(k0 + kb + c2 * 4) * N_TOK + bn + nn];
    }
    __syncthreads();
    #pragma unroll
    for (int kk = 0; kk < 16; kk++) {
      const float4 a4 = *reinterpret_cast<const float4*>(&As[kk][tm]);
      const float4 b4 = *reinterpret_cast<const float4*>(&Bs[kk][tn]);
      const float a[4] = {a4.x, a4.y, a4.z, a4.w};
      const float b[4] = {b4.x, b4.y, b4.z, b4.w};
      #pragma unroll
      for (int i = 0; i < 4; i++)
        #pragma unroll
        for (int j = 0; j < 4; j++)
          acc[i][j] += a[i] * b[j];
    }
    __syncthreads();
  }

  #pragma unroll
  for (int i = 0; i < 4; i++)
    #pragma unroll
    for (int j = 0; j < 4; j++)
      QKV[(by * 64 + tm + i) * N_TOK + bn + tn + j] = acc[i][j] * scl;
}

// ---------------------------------------------------------------------------
// Kernel 2: depthwise 3x3 conv, pad=1, writes d_out (attn added later)
// ---------------------------------------------------------------------------
__global__ __launch_bounds__(256) void dwconv_kernel(
    const float* __restrict__ x, const float* __restrict__ wl,
    float* __restrict__ out)
{
  const int idx = blockIdx.x * 256 + threadIdx.x;   // [c][y][x] over 1M
  const int c  = idx >> 12;
  const int yy = (idx >> 6) & 63;
  const int xx = idx & 63;
  const float* xc = x + c * 4096;
  const float* wc = wl + c * 9;
  float acc = 0.f;
  #pragma unroll
  for (int dy = 0; dy < 3; dy++) {
    const int y = yy + dy - 1;
    if (y < 0 || y > 63) continue;
    #pragma unroll
    for (int dx = 0; dx < 3; dx++) {
      const int x2 = xx + dx - 1;
      if (x2 < 0 || x2 > 63) continue;
      acc += wc[dy * 3 + dx] * xc[y * 64 + x2];
    }
  }
  out[idx] = acc;
}

// ---------------------------------------------------------------------------
// Kernel 3: flash-attention partials with key-split.
// One thread = one query row. K/V tiles (64 keys x 32 d) staged in LDS,
// read back as uniform-address float4 (broadcast, conflict-free).
// Q was pre-scaled by 1/sqrt(32).
// Opart layout: [ks][h][dg(8)][n(4096)][4]  (coalesced float4 per lane)
// ---------------------------------------------------------------------------
__global__ __launch_bounds__(256) void attn_partial(
    const float* __restrict__ QKV,
    float* __restrict__ Opart,
    float* __restrict__ mpart,
    float* __restrict__ lpart)
{
  const int h  = blockIdx.z;
  const int ks = blockIdx.y;
  const int n  = blockIdx.x * 256 + threadIdx.x;

  const float* Q = QKV;
  const float* K = QKV + 256 * N_TOK;
  const float* V = QKV + 512 * N_TOK;

  float q[HDIM];
  #pragma unroll
  for (int d = 0; d < HDIM; d++) q[d] = Q[(h * HDIM + d) * N_TOK + n];

  __shared__ float Ks[HDIM][64];
  __shared__ float Vs[HDIM][64];

  float m = -3.0e38f, l = 0.f;
  float o[HDIM];
  #pragma unroll
  for (int d = 0; d < HDIM; d++) o[d] = 0.f;

  const int k_base = ks * (N_TOK / KSPLIT);   // 1024 keys per split

  for (int kt = 0; kt < N_TOK / KSPLIT; kt += 64) {
    __syncthreads();   // previous tile fully consumed
    {
      const int kk = threadIdx.x & 63;
      const int d0 = threadIdx.x >> 6;        // 0..3
      #pragma unroll
      for (int c2 = 0; c2 < 8; c2++) {
        const int d = c2 * 4 + d0;
        Ks[d][kk] = K[(h * HDIM + d) * N_TOK + k_base + kt + kk];
        Vs[d][kk] = V[(h * HDIM + d) * N_TOK + k_base + kt + kk];
      }
    }
    __syncthreads();

    // scores for 64 keys
    float s[64];
    #pragma unroll
    for (int k4 = 0; k4 < 16; k4++) {
      float s0 = 0.f, s1 = 0.f, s2 = 0.f, s3 = 0.f;
      #pragma unroll
      for (int d = 0; d < HDIM; d++) {
        const float4 kv = *reinterpret_cast<const float4*>(&Ks[d][k4 * 4]);
        s0 += q[d] * kv.x; s1 += q[d] * kv.y;
        s2 += q[d] * kv.z; s3 += q[d] * kv.w;
      }
      s[k4 * 4 + 0] = s0; s[k4 * 4 + 1] = s1;
      s[k4 * 4 + 2] = s2; s[k4 * 4 + 3] = s3;
    }

    // online softmax
    float mt = s[0];
    #pragma unroll
    for (int k = 1; k < 64; k++) mt = fmaxf(mt, s[k]);
    const float mnew = fmaxf(m, mt);
    const float corr = __expf(m - mnew);
    l *= corr;
    #pragma unroll
    for (int d = 0; d < HDIM; d++) o[d] *= corr;
    #pragma unroll
    for (int k = 0; k < 64; k++) { s[k] = __expf(s[k] - mnew); l += s[k]; }
    m = mnew;

    // PV accumulate
    #pragma unroll
    for (int d = 0; d < HDIM; d++) {
      float a = o[d];
      #pragma unroll
      for (int k4 = 0; k4 < 16; k4++) {
        const float4 vv = *reinterpret_cast<const float4*>(&Vs[d][k4 * 4]);
        a += s[k4 * 4 + 0] * vv.x + s[k4 * 4 + 1] * vv.y +
             s[k4 * 4 + 2] * vv.z + s[k4 * 4 + 3] * vv.w;
      }
      o[d] = a;
    }
  }

  #pragma unroll
  for (int dg = 0; dg < 8; dg++) {
    const float4 v4 = make_float4(o[dg * 4], o[dg * 4 + 1], o[dg * 4 + 2], o[dg * 4 + 3]);
    *reinterpret_cast<float4*>(
        &Opart[((((size_t)(ks * HEADS + h) * 8 + dg) * N_TOK) + n) * 4]) = v4;
  }
  mpart[(ks * HEADS + h) * N_TOK + n] = m;
  lpart[(ks * HEADS + h) * N_TOK + n] = l;
}

// ---------------------------------------------------------------------------
// Kernel 4: combine key-split partials -> outb[256][4096] (o = h*32+d major)
// ---------------------------------------------------------------------------
__global__ __launch_bounds__(256) void attn_reduce(
    const float* __restrict__ Opart,
    const float* __restrict__ mpart,
    const float* __restrict__ lpart,
    float* __restrict__ outb)
{
  const int idx = blockIdx.x * 256 + threadIdx.x;   // over 8*4096
  const int h = idx >> 12;
  const int n = idx & 4095;

  float mv[KSPLIT];
  float M = -3.0e38f;
  #pragma unroll
  for (int ks = 0; ks < KSPLIT; ks++) {
    mv[ks] = mpart[(ks * HEADS + h) * N_TOK + n];
    M = fmaxf(M, mv[ks]);
  }
  float w[KSPLIT];
  float l = 0.f;
  #pragma unroll
  for (int ks = 0; ks < KSPLIT; ks++) {
    w[ks] = __expf(mv[ks] - M);
    l += w[ks] * lpart[(ks * HEADS + h) * N_TOK + n];
  }
  const float inv = 1.f / l;

  #pragma unroll
  for (int dg = 0; dg < 8; dg++) {
    float4 a = make_float4(0.f, 0.f, 0.f, 0.f);
    #pragma unroll
    for (int ks = 0; ks < KSPLIT; ks++) {
      const float4 p = *reinterpret_cast<const float4*>(
          &Opart[((((size_t)(ks * HEADS + h) * 8 + dg) * N_TOK) + n) * 4]);
      a.x += w[ks] * p.x; a.y += w[ks] * p.y;
      a.z += w[ks] * p.z; a.w += w[ks] * p.w;
    }
    outb[(h * HDIM + dg * 4 + 0) * N_TOK + n] = a.x * inv;
    outb[(h * HDIM + dg * 4 + 1) * N_TOK + n] = a.y * inv;
    outb[(h * HDIM + dg * 4 + 2) * N_TOK + n] = a.z * inv;
    outb[(h * HDIM + dg * 4 + 3) * N_TOK + n] = a.w * inv;
  }
}

// ---------------------------------------------------------------------------
// Kernel 5: output projection, accumulates onto conv result in d_out.
// d_out[c][n] += sum_o wo[c][o] * outb[o][n]
// ---------------------------------------------------------------------------
__global__ __launch_bounds__(256) void out_gemm_kernel(
    const float* __restrict__ wo,
    const float* __restrict__ outb,
    float* __restrict__ out)
{
  const int bn = blockIdx.x * 64;
  const int bm = blockIdx.y * 64;

  __shared__ float As[16][68];
  __shared__ float Bs[16][64];

  const int t  = threadIdx.x;
  const int tm = (t & 15) * 4;
  const int tn = (t >> 4) * 4;

  float acc[4][4] = {};

  for (int k0 = 0; k0 < C_DIM; k0 += 16) {
    {
      const int r  = t >> 2;
      const int kk = (t & 3) * 4;
      const float4 w4 = *reinterpret_cast<const float4*>(&wo[(bm + r) * C_DIM + k0 + kk]);
      As[kk + 0][r] = w4.x; As[kk + 1][r] = w4.y;
      As[kk + 2][r] = w4.z; As[kk + 3][r] = w4.w;
    }
    {
      const int kb = t >> 6;
      const int nn = t & 63;
      #pragma unroll
      for (int c2 = 0; c2 < 4; c2++)
        Bs[kb + c2 * 4][nn] = outb[(k0 + kb + c2 * 4) * N_TOK + bn + nn];
    }
    __syncthreads();
    #pragma unroll
    for (int kk = 0; kk < 16; kk++) {
      const float4 a4 = *reinterpret_cast<const float4*>(&As[kk][tm]);
      const float4 b4 = *reinterpret_cast<const float4*>(&Bs[kk][tn]);
      const float a[4] = {a4.x, a4.y, a4.z, a4.w};
      const float b[4] = {b4.x, b4.y, b4.z, b4.w};
      #pragma unroll
      for (int i = 0; i < 4; i++)
        #pragma unroll
        for (int j = 0; j < 4; j++)
          acc[i][j] += a[i] * b[j];
    }
    __syncthreads();
  }

  #pragma unroll
  for (int i = 0; i < 4; i++)
    #pragma unroll
    for (int j = 0; j < 4; j++) {
      const int oidx = (bm + tm + i) * N_TOK + bn + tn + j;
      out[oidx] += acc[i][j];   // conv result already there
    }
}

// ---------------------------------------------------------------------------
extern "C" void kernel_launch(void* const* d_in, const int* in_sizes, int n_in,
                              void* d_out, int out_size, void* d_ws, size_t ws_size,
                              hipStream_t stream) {
  const float* x  = (const float*)d_in[0];
  const float* wq = (const float*)d_in[1];
  const float* wk = (const float*)d_in[2];
  const float* wv = (const float*)d_in[3];
  const float* wo = (const float*)d_in[4];
  const float* wl = (const float*)d_in[5];
  float* out = (float*)d_out;
  float* ws  = (float*)d_ws;

  // workspace layout (floats):
  float* QKV   = ws;                                        // 768*4096      = 3,145,728
  float* Opart = QKV + 768 * N_TOK;                         // 4*8*8*4096*4  = 4,194,304
  float* mpart = Opart + (size_t)KSPLIT * HEADS * N_TOK * HDIM;  // 131,072
  float* lpart = mpart + (size_t)KSPLIT * HEADS * N_TOK;         // 131,072
  float* outb  = lpart + (size_t)KSPLIT * HEADS * N_TOK;         // 1,048,576
  // total ~8.65M floats = 34.6 MB of d_ws

  qkv_kernel<<<dim3(64, 12), 256, 0, stream>>>(x, wq, wk, wv, QKV);
  dwconv_kernel<<<4096, 256, 0, stream>>>(x, wl, out);
  attn_partial<<<dim3(16, KSPLIT, 8), 256, 0, stream>>>(QKV, Opart, mpart, lpart);
  attn_reduce<<<(HEADS * N_TOK) / 256, 256, 0, stream>>>(Opart, mpart, lpart, outb);
  out_gemm_kernel<<<dim3(64, 4), 256, 0, stream>>>(wo, outb, out);
}

// Round 2
// 208.376 us; speedup vs baseline: 6.1470x; 6.1470x over previous
//
#include <hip/hip_runtime.h>

#define N_TOK 4096
#define C_DIM 256
#define HEADS 8
#define HDIM  32
#define KSPLIT 2
#define QSCALE 0.17677669529663687f

typedef __attribute__((ext_vector_type(8))) short bf16x8;
typedef __attribute__((ext_vector_type(4))) float f32x4;

static __device__ __forceinline__ unsigned short f2bf(float f) {
  union { float f; unsigned int u; } c; c.f = f;
  return (unsigned short)((c.u + 0x8000u) >> 16);
}
static __device__ __forceinline__ unsigned int pack2(float a, float b) {
  return (unsigned int)f2bf(a) | ((unsigned int)f2bf(b) << 16);
}

// ---------------------------------------------------------------------------
// Kernel 1: fused QKV projection -> bf16.  Q pre-scaled by 1/sqrt(32).
// Qb/Kb/Vb are [256][4096] bf16 (o-major, o = h*32+d).
// ---------------------------------------------------------------------------
__global__ __launch_bounds__(256) void qkv_kernel(
    const float* __restrict__ x,
    const float* __restrict__ wq,
    const float* __restrict__ wk,
    const float* __restrict__ wv,
    unsigned short* __restrict__ Qb,
    unsigned short* __restrict__ Kb,
    unsigned short* __restrict__ Vb)
{
  const int bn = blockIdx.x * 64;
  const int by = blockIdx.y;                       // 0..11 (q:0-3, k:4-7, v:8-11)
  const float* W = (by < 4) ? wq : (by < 8) ? wk : wv;
  unsigned short* O = (by < 4) ? Qb : (by < 8) ? Kb : Vb;
  const int wrow0 = (by & 3) * 64;
  const float scl = (by < 4) ? QSCALE : 1.0f;

  __shared__ float As[16][68];
  __shared__ float Bs[16][64];

  const int t  = threadIdx.x;
  const int tm = (t & 15) * 4;
  const int tn = (t >> 4) * 4;

  float acc[4][4] = {};

  for (int k0 = 0; k0 < C_DIM; k0 += 16) {
    {
      const int r  = t >> 2;
      const int kk = (t & 3) * 4;
      const float4 w4 = *reinterpret_cast<const float4*>(&W[(wrow0 + r) * C_DIM + k0 + kk]);
      As[kk + 0][r] = w4.x; As[kk + 1][r] = w4.y;
      As[kk + 2][r] = w4.z; As[kk + 3][r] = w4.w;
    }
    {
      const int kb = t >> 6;
      const int nn = t & 63;
      #pragma unroll
      for (int c2 = 0; c2 < 4; c2++)
        Bs[kb + c2 * 4][nn] = x[(k0 + kb + c2 * 4) * N_TOK + bn + nn];
    }
    __syncthreads();
    #pragma unroll
    for (int kk = 0; kk < 16; kk++) {
      const float4 a4 = *reinterpret_cast<const float4*>(&As[kk][tm]);
      const float4 b4 = *reinterpret_cast<const float4*>(&Bs[kk][tn]);
      const float a[4] = {a4.x, a4.y, a4.z, a4.w};
      const float b[4] = {b4.x, b4.y, b4.z, b4.w};
      #pragma unroll
      for (int i = 0; i < 4; i++)
        #pragma unroll
        for (int j = 0; j < 4; j++)
          acc[i][j] += a[i] * b[j];
    }
    __syncthreads();
  }

  #pragma unroll
  for (int i = 0; i < 4; i++) {
    const int orow = wrow0 + tm + i;
    ushort4 u;
    u.x = f2bf(acc[i][0] * scl); u.y = f2bf(acc[i][1] * scl);
    u.z = f2bf(acc[i][2] * scl); u.w = f2bf(acc[i][3] * scl);
    *reinterpret_cast<ushort4*>(&O[orow * N_TOK + bn + tn]) = u;
  }
}

// ---------------------------------------------------------------------------
// Kernel 1b: K transpose per head: Kb [h*32+d][n] -> Kt [h][n][d]  (bf16)
// ---------------------------------------------------------------------------
__global__ __launch_bounds__(256) void ktrans_kernel(
    const unsigned short* __restrict__ Kb,
    unsigned short* __restrict__ Kt)
{
  const int h  = blockIdx.y;
  const int nb = blockIdx.x * 64;
  __shared__ unsigned short T[64][36];   // [n][d], padded

  const int t = threadIdx.x;
  {
    const int d  = t >> 3;          // 0..31
    const int n0 = (t & 7) * 8;     // 0..56
    ushort4 a = *reinterpret_cast<const ushort4*>(&Kb[(h * HDIM + d) * N_TOK + nb + n0]);
    ushort4 b = *reinterpret_cast<const ushort4*>(&Kb[(h * HDIM + d) * N_TOK + nb + n0 + 4]);
    T[n0 + 0][d] = a.x; T[n0 + 1][d] = a.y; T[n0 + 2][d] = a.z; T[n0 + 3][d] = a.w;
    T[n0 + 4][d] = b.x; T[n0 + 5][d] = b.y; T[n0 + 6][d] = b.z; T[n0 + 7][d] = b.w;
  }
  __syncthreads();
  {
    const int n  = t & 63;
    const int dg = (t >> 6) * 8;    // 0,8,16,24
    ushort4 u0, u1;
    u0.x = T[n][dg + 0]; u0.y = T[n][dg + 1]; u0.z = T[n][dg + 2]; u0.w = T[n][dg + 3];
    u1.x = T[n][dg + 4]; u1.y = T[n][dg + 5]; u1.z = T[n][dg + 6]; u1.w = T[n][dg + 7];
    *reinterpret_cast<ushort4*>(&Kt[((size_t)h * N_TOK + nb + n) * HDIM + dg]) = u0;
    *reinterpret_cast<ushort4*>(&Kt[((size_t)h * N_TOK + nb + n) * HDIM + dg + 4]) = u1;
  }
}

// ---------------------------------------------------------------------------
// Kernel 2: depthwise 3x3 conv, pad=1, writes d_out (attn added later)
// ---------------------------------------------------------------------------
__global__ __launch_bounds__(256) void dwconv_kernel(
    const float* __restrict__ x, const float* __restrict__ wl,
    float* __restrict__ out)
{
  const int idx = blockIdx.x * 256 + threadIdx.x;
  const int c  = idx >> 12;
  const int yy = (idx >> 6) & 63;
  const int xx = idx & 63;
  const float* xc = x + c * 4096;
  const float* wc = wl + c * 9;
  float acc = 0.f;
  #pragma unroll
  for (int dy = 0; dy < 3; dy++) {
    const int y = yy + dy - 1;
    if (y < 0 || y > 63) continue;
    #pragma unroll
    for (int dx = 0; dx < 3; dx++) {
      const int x2 = xx + dx - 1;
      if (x2 < 0 || x2 > 63) continue;
      acc += wc[dy * 3 + dx] * xc[y * 64 + x2];
    }
  }
  out[idx] = acc;
}

// ---------------------------------------------------------------------------
// Kernel 3: MFMA flash attention partials.
// Wave handles 16 queries; S^T = mfma(K,Q) so softmax stats are lane-local
// to query lane&15.  No __syncthreads (wave-private P buffer in LDS).
// ---------------------------------------------------------------------------
__global__ __launch_bounds__(256) void attn_mfma(
    const unsigned short* __restrict__ Qb,
    const unsigned short* __restrict__ Kt,
    const unsigned short* __restrict__ Vb,
    float* __restrict__ Opart,
    float* __restrict__ mpart,
    float* __restrict__ lpart)
{
  const int h  = blockIdx.z;
  const int ks = blockIdx.y;
  const int w    = threadIdx.x >> 6;
  const int lane = threadIdx.x & 63;
  const int lq   = lane & 15;
  const int g    = lane >> 4;
  const int nq   = blockIdx.x * 64 + w * 16 + lq;

  __shared__ unsigned short Pl[4][16][40];   // per-wave P tile [q][k], 16B-aligned rows

  // Q B-fragment: col q = lq, k-elems d = g*8+j  (hoisted; 8 strided bf16 reads)
  bf16x8 qf;
  {
    const unsigned short* Qh = Qb + h * HDIM * N_TOK;
    #pragma unroll
    for (int j = 0; j < 8; j++) qf[j] = (short)Qh[(g * 8 + j) * N_TOK + nq];
  }

  f32x4 o0 = {0.f, 0.f, 0.f, 0.f};
  f32x4 o1 = {0.f, 0.f, 0.f, 0.f};
  float m = -3.0e38f, l = 0.f;

  const unsigned short* KtH = Kt + (size_t)h * N_TOK * HDIM;
  const unsigned short* VH  = Vb + h * HDIM * N_TOK;

  for (int kt = 0; kt < N_TOK / KSPLIT; kt += 32) {
    const int kb = ks * (N_TOK / KSPLIT) + kt;

    // K A-fragments (direct global, 16B): rows = keys, k-elems = d
    const bf16x8 kf0 = *reinterpret_cast<const bf16x8*>(&KtH[(kb + lq) * HDIM + g * 8]);
    const bf16x8 kf1 = *reinterpret_cast<const bf16x8*>(&KtH[(kb + 16 + lq) * HDIM + g * 8]);

    f32x4 s0 = __builtin_amdgcn_mfma_f32_16x16x32_bf16(kf0, qf, (f32x4){0.f,0.f,0.f,0.f}, 0, 0, 0);
    f32x4 s1 = __builtin_amdgcn_mfma_f32_16x16x32_bf16(kf1, qf, (f32x4){0.f,0.f,0.f,0.f}, 0, 0, 0);

    // online softmax for query lq (keys g*4+r and 16+g*4+r in this lane)
    float pm = fmaxf(fmaxf(fmaxf(s0[0], s0[1]), fmaxf(s0[2], s0[3])),
                     fmaxf(fmaxf(s1[0], s1[1]), fmaxf(s1[2], s1[3])));
    pm = fmaxf(pm, __shfl_xor(pm, 16));
    pm = fmaxf(pm, __shfl_xor(pm, 32));
    const float mnew = fmaxf(m, pm);
    const float corr = __expf(m - mnew);
    m = mnew;

    float p[8];
    #pragma unroll
    for (int r = 0; r < 4; r++) { p[r] = __expf(s0[r] - m); p[4 + r] = __expf(s1[r] - m); }
    float ts = (p[0] + p[1]) + (p[2] + p[3]) + (p[4] + p[5]) + (p[6] + p[7]);
    ts += __shfl_xor(ts, 16);
    ts += __shfl_xor(ts, 32);
    l = l * corr + ts;
    o0 *= corr;
    o1 *= corr;

    // P -> LDS as bf16: lane writes keys {4g..4g+3} and {16+4g..16+4g+3} of row lq
    uint2 w0; w0.x = pack2(p[0], p[1]); w0.y = pack2(p[2], p[3]);
    uint2 w1; w1.x = pack2(p[4], p[5]); w1.y = pack2(p[6], p[7]);
    *reinterpret_cast<uint2*>(&Pl[w][lq][4 * g])      = w0;
    *reinterpret_cast<uint2*>(&Pl[w][lq][16 + 4 * g]) = w1;

    // P B-fragment: col q = lq, k-elems = keys g*8..g*8+7
    const bf16x8 pf = *reinterpret_cast<const bf16x8*>(&Pl[w][lq][8 * g]);

    // V^T A-fragments: rows d (lq / 16+lq), k-elems keys g*8+j  (natural V layout)
    const bf16x8 vf0 = *reinterpret_cast<const bf16x8*>(&VH[lq * N_TOK + kb + g * 8]);
    const bf16x8 vf1 = *reinterpret_cast<const bf16x8*>(&VH[(16 + lq) * N_TOK + kb + g * 8]);

    o0 = __builtin_amdgcn_mfma_f32_16x16x32_bf16(vf0, pf, o0, 0, 0, 0);
    o1 = __builtin_amdgcn_mfma_f32_16x16x32_bf16(vf1, pf, o1, 0, 0, 0);
  }

  // write partials: O^T[d][q], d = frag*16 + g*4 + r
  const int obase = (ks * HEADS + h) * HDIM;
  #pragma unroll
  for (int r = 0; r < 4; r++) {
    Opart[(obase + g * 4 + r) * N_TOK + nq]      = o0[r];
    Opart[(obase + 16 + g * 4 + r) * N_TOK + nq] = o1[r];
  }
  if (g == 0) {
    mpart[(ks * HEADS + h) * N_TOK + nq] = m;
    lpart[(ks * HEADS + h) * N_TOK + nq] = l;
  }
}

// ---------------------------------------------------------------------------
// Kernel 4: combine key-split partials -> outb[256][4096] fp32
// ---------------------------------------------------------------------------
__global__ __launch_bounds__(256) void attn_combine(
    const float* __restrict__ Opart,
    const float* __restrict__ mpart,
    const float* __restrict__ lpart,
    float* __restrict__ outb)
{
  const int idx = blockIdx.x * 256 + threadIdx.x;   // over 8*4096
  const int h = idx >> 12;
  const int n = idx & 4095;

  const float m0 = mpart[h * N_TOK + n];
  const float m1 = mpart[(HEADS + h) * N_TOK + n];
  const float M  = fmaxf(m0, m1);
  const float w0 = __expf(m0 - M);
  const float w1 = __expf(m1 - M);
  const float L  = w0 * lpart[h * N_TOK + n] + w1 * lpart[(HEADS + h) * N_TOK + n];
  const float inv = 1.f / L;

  #pragma unroll
  for (int d = 0; d < HDIM; d++) {
    const float a = Opart[(h * HDIM + d) * N_TOK + n];
    const float b = Opart[((HEADS + h) * HDIM + d) * N_TOK + n];
    outb[(h * HDIM + d) * N_TOK + n] = (w0 * a + w1 * b) * inv;
  }
}

// ---------------------------------------------------------------------------
// Kernel 5: output projection, accumulates onto conv result in d_out.
// ---------------------------------------------------------------------------
__global__ __launch_bounds__(256) void out_gemm_kernel(
    const float* __restrict__ wo,
    const float* __restrict__ outb,
    float* __restrict__ out)
{
  const int bn = blockIdx.x * 64;
  const int bm = blockIdx.y * 64;

  __shared__ float As[16][68];
  __shared__ float Bs[16][64];

  const int t  = threadIdx.x;
  const int tm = (t & 15) * 4;
  const int tn = (t >> 4) * 4;

  float acc[4][4] = {};

  for (int k0 = 0; k0 < C_DIM; k0 += 16) {
    {
      const int r  = t >> 2;
      const int kk = (t & 3) * 4;
      const float4 w4 = *reinterpret_cast<const float4*>(&wo[(bm + r) * C_DIM + k0 + kk]);
      As[kk + 0][r] = w4.x; As[kk + 1][r] = w4.y;
      As[kk + 2][r] = w4.z; As[kk + 3][r] = w4.w;
    }
    {
      const int kb = t >> 6;
      const int nn = t & 63;
      #pragma unroll
      for (int c2 = 0; c2 < 4; c2++)
        Bs[kb + c2 * 4][nn] = outb[(k0 + kb + c2 * 4) * N_TOK + bn + nn];
    }
    __syncthreads();
    #pragma unroll
    for (int kk = 0; kk < 16; kk++) {
      const float4 a4 = *reinterpret_cast<const float4*>(&As[kk][tm]);
      const float4 b4 = *reinterpret_cast<const float4*>(&Bs[kk][tn]);
      const float a[4] = {a4.x, a4.y, a4.z, a4.w};
      const float b[4] = {b4.x, b4.y, b4.z, b4.w};
      #pragma unroll
      for (int i = 0; i < 4; i++)
        #pragma unroll
        for (int j = 0; j < 4; j++)
          acc[i][j] += a[i] * b[j];
    }
    __syncthreads();
  }

  #pragma unroll
  for (int i = 0; i < 4; i++)
    #pragma unroll
    for (int j = 0; j < 4; j++) {
      const int oidx = (bm + tm + i) * N_TOK + bn + tn + j;
      out[oidx] += acc[i][j];
    }
}

// ---------------------------------------------------------------------------
extern "C" void kernel_launch(void* const* d_in, const int* in_sizes, int n_in,
                              void* d_out, int out_size, void* d_ws, size_t ws_size,
                              hipStream_t stream) {
  const float* x  = (const float*)d_in[0];
  const float* wq = (const float*)d_in[1];
  const float* wk = (const float*)d_in[2];
  const float* wv = (const float*)d_in[3];
  const float* wo = (const float*)d_in[4];
  const float* wl = (const float*)d_in[5];
  float* out = (float*)d_out;

  // workspace layout
  float* Opart = (float*)d_ws;                          // 2*8*32*4096 = 2,097,152 f
  float* mpart = Opart + 2097152;                       // 65,536 f
  float* lpart = mpart + 65536;                         // 65,536 f
  float* outb  = lpart + 65536;                         // 1,048,576 f
  unsigned short* Qb = (unsigned short*)(outb + 1048576);   // 1M bf16
  unsigned short* Kb = Qb + 1048576;                        // 1M bf16
  unsigned short* Kt = Kb + 1048576;                        // 1M bf16
  unsigned short* Vb = Kt + 1048576;                        // 1M bf16
  // total ~21.1 MB

  qkv_kernel<<<dim3(64, 12), 256, 0, stream>>>(x, wq, wk, wv, Qb, Kb, Vb);
  ktrans_kernel<<<dim3(64, HEADS), 256, 0, stream>>>(Kb, Kt);
  dwconv_kernel<<<4096, 256, 0, stream>>>(x, wl, out);
  attn_mfma<<<dim3(64, KSPLIT, HEADS), 256, 0, stream>>>(Qb, Kt, Vb, Opart, mpart, lpart);
  attn_combine<<<(HEADS * N_TOK) / 256, 256, 0, stream>>>(Opart, mpart, lpart, outb);
  out_gemm_kernel<<<dim3(64, 4), 256, 0, stream>>>(wo, outb, out);
}